// Round 4
// baseline (864.063 us; speedup 1.0000x reference)
//
#include <hip/hip_runtime.h>

// GraphConv (PyG, aggr='add') + ReLU on MI355X — ALL FP32 per reference dtypes.
//   out = relu( segment_sum(x[src] -> dst) @ W_rel^T + b_rel + x @ W_root^T )
// N=50000, E=800000, D=128. float32 in/out, int edge_index (int32 or int64,
// detected on device).
//
// Round 3: previous rounds misread fp32 inputs as bf16 (contract says
// float32 -> const float*). Full fp32 rewrite. Aggregation happens IN-PLACE
// in d_out (exactly N*D fp32), so no large-workspace assumption. d_ws is used
// only for [flag | transposed W_rel | transposed W_root] = 128 KB + 16 B,
// guarded by ws_size with a weights-from-global fallback GEMM.

#define N_NODES 50000
#define N_EDGES 800000
#define D 128
#define NPB 32      // nodes per gemm block
#define KC 32       // k per chunk; 4 chunks cover K=128

__global__ __launch_bounds__(256) void zero_f4_kernel(float4* __restrict__ p, int n4) {
    int i = blockIdx.x * 256 + threadIdx.x;
    if (i < n4) p[i] = make_float4(0.f, 0.f, 0.f, 0.f);
}

// int64 node-id array => every odd int32 word is 0 (ids < 50000). One thread.
__global__ void detect_kernel(const int* __restrict__ ei, int* __restrict__ flag) {
    if (threadIdx.x == 0 && blockIdx.x == 0) {
        int any = 0;
        for (int i = 0; i < 64; ++i) any |= ei[2 * i + 1];
        flag[0] = (any == 0) ? 1 : 0;
    }
}

// Transpose W[o][k] (row-major fp32) -> pw[k*D + o].
__global__ __launch_bounds__(256) void pack_w_kernel(const float* __restrict__ W,
                                                     float* __restrict__ pw) {
    int idx = blockIdx.x * 256 + threadIdx.x;    // 0..16383
    if (idx >= D * D) return;
    int o = idx >> 7, k = idx & 127;             // reads coalesced in k
    pw[k * D + o] = W[o * D + k];
}

// One wave per edge: lane l adds x[src][2l..2l+1] into out[dst][2l..2l+1].
__global__ __launch_bounds__(256) void scatter_kernel(const float2* __restrict__ x2,
                                                      const int* __restrict__ ei,
                                                      const int* __restrict__ flag,
                                                      float* __restrict__ agg) {
    int wave = threadIdx.x >> 6;
    int lane = threadIdx.x & 63;
    int e = blockIdx.x * 4 + wave;
    if (e >= N_EDGES) return;
    int i64 = flag ? flag[0] : 0;
    int s, d;
    if (i64) { s = ei[2 * e]; d = ei[2 * N_EDGES + 2 * e]; }
    else     { s = ei[e];     d = ei[N_EDGES + e]; }
    if ((unsigned)s >= N_NODES || (unsigned)d >= N_NODES) return;   // never fault
    float2 f = x2[(size_t)s * (D / 2) + lane];
    atomicAdd(&agg[(size_t)d * D + 2 * lane + 0], f.x);
    atomicAdd(&agg[(size_t)d * D + 2 * lane + 1], f.y);
}

// Fused dual GEMM + bias + ReLU, IN-PLACE over d_out (agg rows -> out rows).
// 256 threads, 32 nodes x 128 outs per block, 4x4 register tile, K chunked.
// LDS = 40 KB. Weights pre-transposed in ws: pw[k*D + o].
__global__ __launch_bounds__(256) void GraphConvLayer_55783035240593_kernel(
        const float2* __restrict__ x2,
        const float* __restrict__ pwrel,
        const float* __restrict__ pwroot,
        const float* __restrict__ b_rel,
        float* __restrict__ out) {
    __shared__ float sWrel[KC * D];          // [k][o], 16 KB
    __shared__ float sWroot[KC * D];         // 16 KB
    __shared__ float2 sA[NPB * (KC / 2)];    // [n][k2], 4 KB
    __shared__ float2 sX[NPB * (KC / 2)];    // 4 KB

    int t = threadIdx.x;
    int node0 = blockIdx.x * NPB;
    int tn = t >> 5;   // 0..7  -> nodes tn*4 .. +3
    int to = t & 31;   // 0..31 -> outs  to*4 .. +3

    float acc[4][4];
#pragma unroll
    for (int a = 0; a < 4; ++a)
#pragma unroll
        for (int b = 0; b < 4; ++b) acc[a][b] = 0.0f;

    for (int c = 0; c < 4; ++c) {
        __syncthreads();
        // stage weights: linear float4 copy, coalesced, conflict-free
#pragma unroll
        for (int r = 0; r < 4; ++r) {
            int i = r * 256 + t;             // float4 index, 0..1023
            ((float4*)sWrel)[i]  = ((const float4*)(pwrel  + c * KC * D))[i];
            ((float4*)sWroot)[i] = ((const float4*)(pwroot + c * KC * D))[i];
        }
        // stage node rows: agg (from out, in-place) + x
#pragma unroll
        for (int r = 0; r < 2; ++r) {
            int i = r * 256 + t;             // 0..511
            int n = i >> 4, k2 = i & 15;
            int node = node0 + n;
            float2 av = make_float2(0.f, 0.f), xv = make_float2(0.f, 0.f);
            if (node < N_NODES) {
                av = ((const float2*)out)[(size_t)node * (D / 2) + c * (KC / 2) + k2];
                xv = x2[(size_t)node * (D / 2) + c * (KC / 2) + k2];
            }
            sA[i] = av;
            sX[i] = xv;
        }
        __syncthreads();

#pragma unroll
        for (int k2 = 0; k2 < KC / 2; ++k2) {
            // contiguous 16B/lane across 32 'to' lanes: conflict-free b128
            float4 wr0 = *(const float4*)&sWrel[(2 * k2 + 0) * D + to * 4];
            float4 wr1 = *(const float4*)&sWrel[(2 * k2 + 1) * D + to * 4];
            float4 wt0 = *(const float4*)&sWroot[(2 * k2 + 0) * D + to * 4];
            float4 wt1 = *(const float4*)&sWroot[(2 * k2 + 1) * D + to * 4];
#pragma unroll
            for (int ni = 0; ni < 4; ++ni) {
                float2 a  = sA[(tn * 4 + ni) * (KC / 2) + k2];   // broadcast
                float2 xx = sX[(tn * 4 + ni) * (KC / 2) + k2];
                acc[ni][0] += a.x * wr0.x + a.y * wr1.x + xx.x * wt0.x + xx.y * wt1.x;
                acc[ni][1] += a.x * wr0.y + a.y * wr1.y + xx.x * wt0.y + xx.y * wt1.y;
                acc[ni][2] += a.x * wr0.z + a.y * wr1.z + xx.x * wt0.z + xx.y * wt1.z;
                acc[ni][3] += a.x * wr0.w + a.y * wr1.w + xx.x * wt0.w + xx.y * wt1.w;
            }
        }
    }

    int o0 = to * 4;
    float4 bias = *(const float4*)&b_rel[o0];
#pragma unroll
    for (int ni = 0; ni < 4; ++ni) {
        int node = node0 + tn * 4 + ni;
        if (node >= N_NODES) continue;
        float4 v;
        v.x = fmaxf(acc[ni][0] + bias.x, 0.f);
        v.y = fmaxf(acc[ni][1] + bias.y, 0.f);
        v.z = fmaxf(acc[ni][2] + bias.z, 0.f);
        v.w = fmaxf(acc[ni][3] + bias.w, 0.f);
        *(float4*)&out[(size_t)node * D + o0] = v;
    }
}

// Fallback GEMM when ws can't even hold packed weights: 1 node per 128-thread
// block, weights straight from global (L2-hot). Correct, not fast.
__global__ __launch_bounds__(128) void gemm_fallback_kernel(const float* __restrict__ x,
                                                            const float* __restrict__ Wrel,
                                                            const float* __restrict__ Wroot,
                                                            const float* __restrict__ b_rel,
                                                            float* __restrict__ out) {
    __shared__ float rowA[D];
    __shared__ float rowX[D];
    int node = blockIdx.x;
    int o = threadIdx.x;
    rowA[o] = out[(size_t)node * D + o];
    rowX[o] = x[(size_t)node * D + o];
    __syncthreads();
    float acc = b_rel[o];
    const float4* wr = (const float4*)&Wrel[o * D];
    const float4* wt = (const float4*)&Wroot[o * D];
#pragma unroll 8
    for (int k4 = 0; k4 < D / 4; ++k4) {
        float4 w = wr[k4], u = wt[k4];
        const float* a = &rowA[k4 * 4];
        const float* xx = &rowX[k4 * 4];
        acc += a[0] * w.x + a[1] * w.y + a[2] * w.z + a[3] * w.w
             + xx[0] * u.x + xx[1] * u.y + xx[2] * u.z + xx[3] * u.w;
    }
    __syncthreads();
    out[(size_t)node * D + o] = fmaxf(acc, 0.f);
}

extern "C" void kernel_launch(void* const* d_in, const int* in_sizes, int n_in,
                              void* d_out, int out_size, void* d_ws, size_t ws_size,
                              hipStream_t stream) {
    const float* x      = (const float*)d_in[0];
    const int*   ei     = (const int*)d_in[1];
    const float* W_rel  = (const float*)d_in[2];
    const float* b_rel  = (const float*)d_in[3];
    const float* W_root = (const float*)d_in[4];
    float*       out    = (float*)d_out;

    // ws layout: [flag int @0 | pad | pwrel 64KB @16 | pwroot 64KB]
    int*   flag   = (int*)d_ws;
    float* pwrel  = (float*)((char*)d_ws + 16);
    float* pwroot = pwrel + D * D;
    bool have_flag = ws_size >= 4;
    bool have_pw   = ws_size >= 16 + 2 * (size_t)D * D * sizeof(float);

    // 1) zero agg (in d_out)
    int n4 = N_NODES * D / 4;
    zero_f4_kernel<<<(n4 + 255) / 256, 256, 0, stream>>>((float4*)out, n4);

    // 2) dtype-of-edge-index detection + weight transpose
    if (have_flag) detect_kernel<<<1, 64, 0, stream>>>(ei, flag);
    if (have_pw) {
        pack_w_kernel<<<64, 256, 0, stream>>>(W_rel, pwrel);
        pack_w_kernel<<<64, 256, 0, stream>>>(W_root, pwroot);
    }

    // 3) scatter-add x[src] into out[dst]
    scatter_kernel<<<N_EDGES / 4, 256, 0, stream>>>((const float2*)x, ei,
                                                    have_flag ? flag : nullptr, out);

    // 4) in-place fused dual GEMM + bias + ReLU
    if (have_pw) {
        int blocks = (N_NODES + NPB - 1) / NPB;   // 1563
        GraphConvLayer_55783035240593_kernel<<<blocks, 256, 0, stream>>>(
            (const float2*)x, pwrel, pwroot, b_rel, out);
    } else {
        gemm_fallback_kernel<<<N_NODES, 128, 0, stream>>>(x, W_rel, W_root, b_rel, out);
    }
}

// Round 5
// 431.377 us; speedup vs baseline: 2.0030x; 2.0030x over previous
//
#include <hip/hip_runtime.h>

// GraphConv (PyG, aggr='add') + ReLU on MI355X — fp32 per reference dtypes.
//   out = relu( segment_sum(x[src] -> dst) @ W_rel^T + b_rel + x @ W_root^T )
// N=50000, E=800000, D=128.
//
// Round 4: scatter_kernel was 654/864 µs, atomic-op bound (102.4M device-scope
// fp32 atomics, WRITE_SIZE = 1 KB/edge RMW). Replace with per-launch CSR
// binning + register gather: histogram -> shfl prefix scan -> reorder ->
// one-wave-per-node gather (zero atomics on the feature data).
// ws (~3.7 MB): [flag | pwrelT | pwrootT | deg/cursor | offsets | csr_src],
// guarded by ws_size with the round-3 atomic path as fallback.

#define N_NODES 50000
#define N_EDGES 800000
#define D 128
#define NPB 32      // nodes per gemm block
#define KC 32       // k per chunk; 4 chunks cover K=128

// ---------------- utility ----------------
__global__ __launch_bounds__(256) void zero_f4_kernel(float4* __restrict__ p, int n4) {
    int i = blockIdx.x * 256 + threadIdx.x;
    if (i < n4) p[i] = make_float4(0.f, 0.f, 0.f, 0.f);
}

__global__ __launch_bounds__(256) void zero_i_kernel(int* __restrict__ p, int n) {
    int i = blockIdx.x * 256 + threadIdx.x;
    if (i < n) p[i] = 0;
}

// int64 node-id array => every odd int32 word is 0 (ids < 50000). One thread.
__global__ void detect_kernel(const int* __restrict__ ei, int* __restrict__ flag) {
    if (threadIdx.x == 0 && blockIdx.x == 0) {
        int any = 0;
        for (int i = 0; i < 64; ++i) any |= ei[2 * i + 1];
        flag[0] = (any == 0) ? 1 : 0;
    }
}

// Transpose W[o][k] (row-major fp32) -> pw[k*D + o].
__global__ __launch_bounds__(256) void pack_w_kernel(const float* __restrict__ W,
                                                     float* __restrict__ pw) {
    int idx = blockIdx.x * 256 + threadIdx.x;    // 0..16383
    if (idx >= D * D) return;
    int o = idx >> 7, k = idx & 127;
    pw[k * D + o] = W[o * D + k];
}

__device__ __forceinline__ void edge_ids(const int* __restrict__ ei, int e, int i64,
                                         int& s, int& d) {
    if (i64) { s = ei[2 * e]; d = ei[2 * N_EDGES + 2 * e]; }
    else     { s = ei[e];     d = ei[N_EDGES + e]; }
}

// ---------------- CSR build ----------------
__global__ __launch_bounds__(256) void hist_kernel(const int* __restrict__ ei,
                                                   const int* __restrict__ flag,
                                                   int* __restrict__ deg) {
    int e = blockIdx.x * 256 + threadIdx.x;
    if (e >= N_EDGES) return;
    int s, d;
    edge_ids(ei, e, flag[0], s, d);
    if ((unsigned)s >= N_NODES || (unsigned)d >= N_NODES) return;
    atomicAdd(&deg[d], 1);
}

__device__ __forceinline__ int wave_iscan(int v, int lane) {
#pragma unroll
    for (int off = 1; off < 64; off <<= 1) {
        int u = __shfl_up(v, off, 64);
        if (lane >= off) v += u;
    }
    return v;
}

// Single-block inclusive scan: offsets[0]=0, offsets[i+1]=sum(deg[0..i]).
__global__ __launch_bounds__(1024) void scan_kernel(const int* __restrict__ deg,
                                                    int* __restrict__ offsets) {
    __shared__ int wsum[16];
    __shared__ int base_s;
    int t = threadIdx.x, lane = t & 63, w = t >> 6;
    if (t == 0) { base_s = 0; offsets[0] = 0; }
    __syncthreads();
    for (int c0 = 0; c0 < N_NODES; c0 += 1024) {
        int idx = c0 + t;
        int v = (idx < N_NODES) ? deg[idx] : 0;
        int inc = wave_iscan(v, lane);
        if (lane == 63) wsum[w] = inc;
        __syncthreads();
        if (w == 0) {
            int s = (lane < 16) ? wsum[lane] : 0;
            int si = wave_iscan(s, lane);
            if (lane < 16) wsum[lane] = si - s;   // exclusive wave base
        }
        __syncthreads();
        int tot = base_s + wsum[w] + inc;         // inclusive through this thread
        if (idx < N_NODES) offsets[idx + 1] = tot;
        __syncthreads();
        if (t == 1023) base_s = tot;              // chunk total carried forward
        __syncthreads();
    }
}

__global__ __launch_bounds__(256) void copy_kernel(const int* __restrict__ offsets,
                                                   int* __restrict__ cursor) {
    int i = blockIdx.x * 256 + threadIdx.x;
    if (i < N_NODES) cursor[i] = offsets[i];
}

__global__ __launch_bounds__(256) void reorder_kernel(const int* __restrict__ ei,
                                                      const int* __restrict__ flag,
                                                      int* __restrict__ cursor,
                                                      int* __restrict__ csr_src) {
    int e = blockIdx.x * 256 + threadIdx.x;
    if (e >= N_EDGES) return;
    int s, d;
    edge_ids(ei, e, flag[0], s, d);
    if ((unsigned)s >= N_NODES || (unsigned)d >= N_NODES) return;
    int pos = atomicAdd(&cursor[d], 1);
    csr_src[pos] = s;
}

// One wave per node: register-accumulate all in-edges, one 512 B store.
__global__ __launch_bounds__(256) void gather_kernel(const float2* __restrict__ x2,
                                                     const int* __restrict__ csr_src,
                                                     const int* __restrict__ offsets,
                                                     float2* __restrict__ agg2) {
    int node = blockIdx.x * 4 + (threadIdx.x >> 6);
    int lane = threadIdx.x & 63;
    if (node >= N_NODES) return;
    int beg = offsets[node], end = offsets[node + 1];
    float2 acc = make_float2(0.f, 0.f);
    for (int e = beg; e < end; ++e) {
        int s = csr_src[e];                       // wave-uniform -> broadcast
        float2 f = x2[(size_t)s * (D / 2) + lane];
        acc.x += f.x;
        acc.y += f.y;
    }
    agg2[(size_t)node * (D / 2) + lane] = acc;
}

// ---------------- fallback aggregation (tiny ws) ----------------
__global__ __launch_bounds__(256) void scatter_kernel(const float2* __restrict__ x2,
                                                      const int* __restrict__ ei,
                                                      const int* __restrict__ flag,
                                                      float* __restrict__ agg) {
    int wave = threadIdx.x >> 6;
    int lane = threadIdx.x & 63;
    int e = blockIdx.x * 4 + wave;
    if (e >= N_EDGES) return;
    int s, d;
    edge_ids(ei, e, flag ? flag[0] : 0, s, d);
    if ((unsigned)s >= N_NODES || (unsigned)d >= N_NODES) return;
    float2 f = x2[(size_t)s * (D / 2) + lane];
    atomicAdd(&agg[(size_t)d * D + 2 * lane + 0], f.x);
    atomicAdd(&agg[(size_t)d * D + 2 * lane + 1], f.y);
}

// ---------------- fused dual GEMM + bias + ReLU (in-place over d_out) -------
__global__ __launch_bounds__(256) void GraphConvLayer_55783035240593_kernel(
        const float2* __restrict__ x2,
        const float* __restrict__ pwrel,
        const float* __restrict__ pwroot,
        const float* __restrict__ b_rel,
        float* __restrict__ out) {
    __shared__ float sWrel[KC * D];          // [k][o], 16 KB
    __shared__ float sWroot[KC * D];         // 16 KB
    __shared__ float2 sA[NPB * (KC / 2)];    // [n][k2], 4 KB
    __shared__ float2 sX[NPB * (KC / 2)];    // 4 KB

    int t = threadIdx.x;
    int node0 = blockIdx.x * NPB;
    int tn = t >> 5;   // 0..7  -> nodes tn*4 .. +3
    int to = t & 31;   // 0..31 -> outs  to*4 .. +3

    float acc[4][4];
#pragma unroll
    for (int a = 0; a < 4; ++a)
#pragma unroll
        for (int b = 0; b < 4; ++b) acc[a][b] = 0.0f;

    for (int c = 0; c < 4; ++c) {
        __syncthreads();
#pragma unroll
        for (int r = 0; r < 4; ++r) {
            int i = r * 256 + t;             // float4 index, 0..1023
            ((float4*)sWrel)[i]  = ((const float4*)(pwrel  + c * KC * D))[i];
            ((float4*)sWroot)[i] = ((const float4*)(pwroot + c * KC * D))[i];
        }
#pragma unroll
        for (int r = 0; r < 2; ++r) {
            int i = r * 256 + t;             // 0..511
            int n = i >> 4, k2 = i & 15;
            int node = node0 + n;
            float2 av = make_float2(0.f, 0.f), xv = make_float2(0.f, 0.f);
            if (node < N_NODES) {
                av = ((const float2*)out)[(size_t)node * (D / 2) + c * (KC / 2) + k2];
                xv = x2[(size_t)node * (D / 2) + c * (KC / 2) + k2];
            }
            sA[i] = av;
            sX[i] = xv;
        }
        __syncthreads();

#pragma unroll
        for (int k2 = 0; k2 < KC / 2; ++k2) {
            float4 wr0 = *(const float4*)&sWrel[(2 * k2 + 0) * D + to * 4];
            float4 wr1 = *(const float4*)&sWrel[(2 * k2 + 1) * D + to * 4];
            float4 wt0 = *(const float4*)&sWroot[(2 * k2 + 0) * D + to * 4];
            float4 wt1 = *(const float4*)&sWroot[(2 * k2 + 1) * D + to * 4];
#pragma unroll
            for (int ni = 0; ni < 4; ++ni) {
                float2 a  = sA[(tn * 4 + ni) * (KC / 2) + k2];
                float2 xx = sX[(tn * 4 + ni) * (KC / 2) + k2];
                acc[ni][0] += a.x * wr0.x + a.y * wr1.x + xx.x * wt0.x + xx.y * wt1.x;
                acc[ni][1] += a.x * wr0.y + a.y * wr1.y + xx.x * wt0.y + xx.y * wt1.y;
                acc[ni][2] += a.x * wr0.z + a.y * wr1.z + xx.x * wt0.z + xx.y * wt1.z;
                acc[ni][3] += a.x * wr0.w + a.y * wr1.w + xx.x * wt0.w + xx.y * wt1.w;
            }
        }
    }

    int o0 = to * 4;
    float4 bias = *(const float4*)&b_rel[o0];
#pragma unroll
    for (int ni = 0; ni < 4; ++ni) {
        int node = node0 + tn * 4 + ni;
        if (node >= N_NODES) continue;
        float4 v;
        v.x = fmaxf(acc[ni][0] + bias.x, 0.f);
        v.y = fmaxf(acc[ni][1] + bias.y, 0.f);
        v.z = fmaxf(acc[ni][2] + bias.z, 0.f);
        v.w = fmaxf(acc[ni][3] + bias.w, 0.f);
        *(float4*)&out[(size_t)node * D + o0] = v;
    }
}

// Fallback GEMM when ws can't hold packed weights.
__global__ __launch_bounds__(128) void gemm_fallback_kernel(const float* __restrict__ x,
                                                            const float* __restrict__ Wrel,
                                                            const float* __restrict__ Wroot,
                                                            const float* __restrict__ b_rel,
                                                            float* __restrict__ out) {
    __shared__ float rowA[D];
    __shared__ float rowX[D];
    int node = blockIdx.x;
    int o = threadIdx.x;
    rowA[o] = out[(size_t)node * D + o];
    rowX[o] = x[(size_t)node * D + o];
    __syncthreads();
    float acc = b_rel[o];
    const float4* wr = (const float4*)&Wrel[o * D];
    const float4* wt = (const float4*)&Wroot[o * D];
#pragma unroll 8
    for (int k4 = 0; k4 < D / 4; ++k4) {
        float4 w = wr[k4], u = wt[k4];
        const float* a = &rowA[k4 * 4];
        const float* xx = &rowX[k4 * 4];
        acc += a[0] * w.x + a[1] * w.y + a[2] * w.z + a[3] * w.w
             + xx[0] * u.x + xx[1] * u.y + xx[2] * u.z + xx[3] * u.w;
    }
    __syncthreads();
    out[(size_t)node * D + o] = fmaxf(acc, 0.f);
}

extern "C" void kernel_launch(void* const* d_in, const int* in_sizes, int n_in,
                              void* d_out, int out_size, void* d_ws, size_t ws_size,
                              hipStream_t stream) {
    const float* x      = (const float*)d_in[0];
    const int*   ei     = (const int*)d_in[1];
    const float* W_rel  = (const float*)d_in[2];
    const float* b_rel  = (const float*)d_in[3];
    const float* W_root = (const float*)d_in[4];
    float*       out    = (float*)d_out;

    // ws layout (16 B aligned chunks):
    //   flag(16) | pwrel 64K | pwroot 64K | deg/cursor 50000i | offsets 50001i | csr_src 800000i
    char* p = (char*)d_ws;
    int*   flag    = (int*)p;                    size_t o0 = 16;
    float* pwrel   = (float*)(p + o0);           o0 += (size_t)D * D * 4;
    float* pwroot  = (float*)(p + o0);           o0 += (size_t)D * D * 4;
    int*   deg     = (int*)(p + o0);             o0 += (size_t)N_NODES * 4;
    int*   offsets = (int*)(p + o0);             o0 += ((size_t)N_NODES + 1) * 4 + 12;
    o0 &= ~15ull;
    int*   csr_src = (int*)(p + o0);             o0 += (size_t)N_EDGES * 4;
    const size_t need_csr = o0;
    const size_t need_pw  = 16 + 2 * (size_t)D * D * 4;

    bool have_flag = ws_size >= 16;
    bool have_pw   = ws_size >= need_pw;
    bool have_csr  = ws_size >= need_csr;

    if (have_flag) detect_kernel<<<1, 64, 0, stream>>>(ei, flag);
    if (have_pw) {
        pack_w_kernel<<<64, 256, 0, stream>>>(W_rel, pwrel);
        pack_w_kernel<<<64, 256, 0, stream>>>(W_root, pwroot);
    }

    if (have_csr) {
        // CSR build + gather aggregation (no feature atomics)
        zero_i_kernel<<<(N_NODES + 255) / 256, 256, 0, stream>>>(deg, N_NODES);
        hist_kernel<<<(N_EDGES + 255) / 256, 256, 0, stream>>>(ei, flag, deg);
        scan_kernel<<<1, 1024, 0, stream>>>(deg, offsets);
        copy_kernel<<<(N_NODES + 255) / 256, 256, 0, stream>>>(offsets, deg); // deg = cursor
        reorder_kernel<<<(N_EDGES + 255) / 256, 256, 0, stream>>>(ei, flag, deg, csr_src);
        gather_kernel<<<(N_NODES + 3) / 4, 256, 0, stream>>>((const float2*)x, csr_src,
                                                             offsets, (float2*)out);
    } else {
        // fallback: zero agg then atomic scatter
        int n4 = N_NODES * D / 4;
        zero_f4_kernel<<<(n4 + 255) / 256, 256, 0, stream>>>((float4*)out, n4);
        scatter_kernel<<<N_EDGES / 4, 256, 0, stream>>>((const float2*)x, ei,
                                                        have_flag ? flag : nullptr, out);
    }

    if (have_pw) {
        int blocks = (N_NODES + NPB - 1) / NPB;   // 1563
        GraphConvLayer_55783035240593_kernel<<<blocks, 256, 0, stream>>>(
            (const float2*)x, pwrel, pwroot, b_rel, out);
    } else {
        gemm_fallback_kernel<<<N_NODES, 128, 0, stream>>>(x, W_rel, W_root, b_rel, out);
    }
}

// Round 6
// 328.925 us; speedup vs baseline: 2.6269x; 1.3115x over previous
//
#include <hip/hip_runtime.h>
#include <hip/hip_bf16.h>

// GraphConv (PyG, aggr='add') + ReLU on MI355X — fp32 in/out, bf16 internals.
//   out = relu( segment_sum(x[src] -> dst) @ W_rel^T + b_rel + x @ W_root^T )
// N=50000, E=800000, D=128.
//
// Round 6: GEMM was 132 µs fp32-VALU latency-bound (no fp32 MFMA on CDNA4).
// Convert x/agg to bf16 (threshold 0.4975 is bf16-grade), pre-pack weights in
// MFMA B-fragment order, zero-LDS MFMA GEMM (1 wave = 16 nodes x 128 outs).
// Gather reads bf16 x (half traffic), stores bf16 agg. CSR scan now also
// initializes the reorder cursor (one fewer launch).
// Tiering by ws_size: full MFMA path (~29.3 MB) -> round-5 CSR+fp32 path
// (~3.7 MB) -> atomic fallback.

#define N_NODES 50000
#define N_EDGES 800000
#define D 128
#define NPB 32      // nodes per fp32-gemm block (mid tier)
#define KC 32       // k per chunk (mid tier)

typedef __attribute__((ext_vector_type(8))) short short8;   // 8 bf16 = 4 VGPRs
typedef __attribute__((ext_vector_type(4))) float floatx4;

__device__ __forceinline__ float bf2f(unsigned short u) {
    return __uint_as_float((unsigned int)u << 16);
}
__device__ __forceinline__ unsigned short f2bf(float f) {
    __hip_bfloat16 h = __float2bfloat16(f);
    return *(unsigned short*)&h;
}

// ---------------- utility ----------------
__global__ __launch_bounds__(256) void zero_f4_kernel(float4* __restrict__ p, int n4) {
    int i = blockIdx.x * 256 + threadIdx.x;
    if (i < n4) p[i] = make_float4(0.f, 0.f, 0.f, 0.f);
}

__global__ __launch_bounds__(256) void zero_i_kernel(int* __restrict__ p, int n) {
    int i = blockIdx.x * 256 + threadIdx.x;
    if (i < n) p[i] = 0;
}

// int64 node-id array => every odd int32 word is 0 (ids < 50000). One thread.
__global__ void detect_kernel(const int* __restrict__ ei, int* __restrict__ flag) {
    if (threadIdx.x == 0 && blockIdx.x == 0) {
        int any = 0;
        for (int i = 0; i < 64; ++i) any |= ei[2 * i + 1];
        flag[0] = (any == 0) ? 1 : 0;
    }
}

__device__ __forceinline__ void edge_ids(const int* __restrict__ ei, int e, int i64,
                                         int& s, int& d) {
    if (i64) { s = ei[2 * e]; d = ei[2 * N_EDGES + 2 * e]; }
    else     { s = ei[e];     d = ei[N_EDGES + e]; }
}

// ---------------- CSR build ----------------
__global__ __launch_bounds__(256) void hist_kernel(const int* __restrict__ ei,
                                                   const int* __restrict__ flag,
                                                   int* __restrict__ deg) {
    int e = blockIdx.x * 256 + threadIdx.x;
    if (e >= N_EDGES) return;
    int s, d;
    edge_ids(ei, e, flag[0], s, d);
    if ((unsigned)s >= N_NODES || (unsigned)d >= N_NODES) return;
    atomicAdd(&deg[d], 1);
}

__device__ __forceinline__ int wave_iscan(int v, int lane) {
#pragma unroll
    for (int off = 1; off < 64; off <<= 1) {
        int u = __shfl_up(v, off, 64);
        if (lane >= off) v += u;
    }
    return v;
}

// Single-block scan. offsets[0]=0, offsets[i+1]=incl sum; cursor[i]=excl sum.
// cursor may alias deg (each thread rewrites only its own element).
__global__ __launch_bounds__(1024) void scan_kernel(const int* __restrict__ deg,
                                                    int* __restrict__ offsets,
                                                    int* __restrict__ cursor) {
    __shared__ int wsum[16];
    __shared__ int base_s;
    int t = threadIdx.x, lane = t & 63, w = t >> 6;
    if (t == 0) { base_s = 0; offsets[0] = 0; }
    __syncthreads();
    for (int c0 = 0; c0 < N_NODES; c0 += 1024) {
        int idx = c0 + t;
        int v = (idx < N_NODES) ? deg[idx] : 0;
        int inc = wave_iscan(v, lane);
        if (lane == 63) wsum[w] = inc;
        __syncthreads();
        if (w == 0) {
            int s = (lane < 16) ? wsum[lane] : 0;
            int si = wave_iscan(s, lane);
            if (lane < 16) wsum[lane] = si - s;   // exclusive wave base
        }
        __syncthreads();
        int tot = base_s + wsum[w] + inc;         // inclusive through this thread
        if (idx < N_NODES) {
            offsets[idx + 1] = tot;
            cursor[idx] = tot - v;                // exclusive prefix
        }
        __syncthreads();
        if (t == 1023) base_s = tot;
        __syncthreads();
    }
}

__global__ __launch_bounds__(256) void reorder_kernel(const int* __restrict__ ei,
                                                      const int* __restrict__ flag,
                                                      int* __restrict__ cursor,
                                                      int* __restrict__ csr_src) {
    int e = blockIdx.x * 256 + threadIdx.x;
    if (e >= N_EDGES) return;
    int s, d;
    edge_ids(ei, e, flag[0], s, d);
    if ((unsigned)s >= N_NODES || (unsigned)d >= N_NODES) return;
    int pos = atomicAdd(&cursor[d], 1);
    csr_src[pos] = s;
}

// ---------------- full tier: bf16 + MFMA ----------------
// x fp32 -> bf16 (packed ushort2 per thread).
__global__ __launch_bounds__(256) void cvt_x_kernel(const float2* __restrict__ x2,
                                                    ushort2* __restrict__ xb2) {
    int i = blockIdx.x * 256 + threadIdx.x;    // 0 .. N*D/2-1
    if (i >= N_NODES * (D / 2)) return;
    float2 f = x2[i];
    xb2[i] = make_ushort2(f2bf(f.x), f2bf(f.y));
}

// Pack [W_rel | W_root] (fp32 [out][in]) into MFMA B-fragment order, bf16:
// pwc[((t*8 + n0)*64 + lane)*8 + j] = W_cat[n0*16 + (lane&15)][t*32 + (lane>>4)*8 + j]
__global__ __launch_bounds__(256) void pack_frag_kernel(const float* __restrict__ Wrel,
                                                        const float* __restrict__ Wroot,
                                                        unsigned short* __restrict__ pwc) {
    int idx = blockIdx.x * 256 + threadIdx.x;   // 0..32767
    if (idx >= 8 * 8 * 64 * 8) return;
    int j    = idx & 7;
    int lane = (idx >> 3) & 63;
    int n0   = (idx >> 9) & 7;
    int t    = idx >> 12;
    int n = n0 * 16 + (lane & 15);
    int k = t * 32 + (lane >> 4) * 8 + j;
    float w = (k < D) ? Wrel[n * D + k] : Wroot[n * D + (k - D)];
    pwc[idx] = f2bf(w);
}

// One wave per node: accumulate in-edges in fp32 registers, store bf16 row.
__global__ __launch_bounds__(256) void gather_bf16_kernel(const ushort2* __restrict__ xb2,
                                                          const int* __restrict__ csr_src,
                                                          const int* __restrict__ offsets,
                                                          ushort2* __restrict__ aggb2) {
    int node = blockIdx.x * 4 + (threadIdx.x >> 6);
    int lane = threadIdx.x & 63;
    if (node >= N_NODES) return;
    int beg = offsets[node], end = offsets[node + 1];
    float ax = 0.f, ay = 0.f;
    for (int e = beg; e < end; ++e) {
        int s = csr_src[e];                       // wave-uniform -> broadcast
        ushort2 u = xb2[(size_t)s * (D / 2) + lane];
        ax += bf2f(u.x);
        ay += bf2f(u.y);
    }
    aggb2[(size_t)node * (D / 2) + lane] = make_ushort2(f2bf(ax), f2bf(ay));
}

// MFMA GEMM: C[50000x128] = [aggb | xb] (50000x256) @ W_cat^T + b, relu.
// 1 wave = 16 nodes x 128 outs; 8 k-steps of 32; no LDS; acc in 32 VGPRs.
// Layouts (verified, learn_hip m89/m120): A[m=lane&15][k=quad*8+j],
// B^T rows same shape, D: col=lane&15 (out), row=quad*4+reg (node).
__global__ __launch_bounds__(256) void GraphConvLayer_55783035240593_kernel(
        const unsigned short* __restrict__ aggb,
        const unsigned short* __restrict__ xb,
        const unsigned short* __restrict__ pwc,
        const float* __restrict__ b_rel,
        float* __restrict__ out) {
    int wid  = threadIdx.x >> 6;
    int lane = threadIdx.x & 63;
    int nodebase = blockIdx.x * 64 + wid * 16;
    if (nodebase >= N_NODES) return;            // 50000 % 16 == 0
    int m = lane & 15, quad = lane >> 4;

    const unsigned short* arow = aggb + (size_t)(nodebase + m) * D + quad * 8;
    const unsigned short* xrow = xb   + (size_t)(nodebase + m) * D + quad * 8;

    floatx4 acc[8];
#pragma unroll
    for (int n0 = 0; n0 < 8; ++n0) acc[n0] = (floatx4){0.f, 0.f, 0.f, 0.f};

#pragma unroll
    for (int t = 0; t < 8; ++t) {
        const unsigned short* asrc = (t < 4) ? (arow + t * 32) : (xrow + (t - 4) * 32);
        short8 afrag = *(const short8*)asrc;                       // 16 B
        const unsigned short* bbase = pwc + ((size_t)t * 8 * 64 + lane) * 8;
#pragma unroll
        for (int n0 = 0; n0 < 8; ++n0) {
            short8 bfrag = *(const short8*)(bbase + (size_t)n0 * 64 * 8);
            acc[n0] = __builtin_amdgcn_mfma_f32_16x16x32_bf16(afrag, bfrag, acc[n0], 0, 0, 0);
        }
    }

#pragma unroll
    for (int n0 = 0; n0 < 8; ++n0) {
        int n = n0 * 16 + m;                     // output feature
        float bias = b_rel[n];
#pragma unroll
        for (int r = 0; r < 4; ++r) {
            int node = nodebase + quad * 4 + r;
            out[(size_t)node * D + n] = fmaxf(acc[n0][r] + bias, 0.f);
        }
    }
}

// ---------------- mid tier: fp32 CSR + VALU GEMM (round-5 path) ----------------
__global__ __launch_bounds__(256) void pack_w_kernel(const float* __restrict__ W,
                                                     float* __restrict__ pw) {
    int idx = blockIdx.x * 256 + threadIdx.x;
    if (idx >= D * D) return;
    int o = idx >> 7, k = idx & 127;
    pw[k * D + o] = W[o * D + k];
}

__global__ __launch_bounds__(256) void gather_kernel(const float2* __restrict__ x2,
                                                     const int* __restrict__ csr_src,
                                                     const int* __restrict__ offsets,
                                                     float2* __restrict__ agg2) {
    int node = blockIdx.x * 4 + (threadIdx.x >> 6);
    int lane = threadIdx.x & 63;
    if (node >= N_NODES) return;
    int beg = offsets[node], end = offsets[node + 1];
    float2 acc = make_float2(0.f, 0.f);
    for (int e = beg; e < end; ++e) {
        int s = csr_src[e];
        float2 f = x2[(size_t)s * (D / 2) + lane];
        acc.x += f.x;
        acc.y += f.y;
    }
    agg2[(size_t)node * (D / 2) + lane] = acc;
}

__global__ __launch_bounds__(256) void scatter_kernel(const float2* __restrict__ x2,
                                                      const int* __restrict__ ei,
                                                      const int* __restrict__ flag,
                                                      float* __restrict__ agg) {
    int wave = threadIdx.x >> 6;
    int lane = threadIdx.x & 63;
    int e = blockIdx.x * 4 + wave;
    if (e >= N_EDGES) return;
    int s, d;
    edge_ids(ei, e, flag ? flag[0] : 0, s, d);
    if ((unsigned)s >= N_NODES || (unsigned)d >= N_NODES) return;
    float2 f = x2[(size_t)s * (D / 2) + lane];
    atomicAdd(&agg[(size_t)d * D + 2 * lane + 0], f.x);
    atomicAdd(&agg[(size_t)d * D + 2 * lane + 1], f.y);
}

__global__ __launch_bounds__(256) void gemm_f32_kernel(
        const float2* __restrict__ x2,
        const float* __restrict__ pwrel,
        const float* __restrict__ pwroot,
        const float* __restrict__ b_rel,
        float* __restrict__ out) {
    __shared__ float sWrel[KC * D];
    __shared__ float sWroot[KC * D];
    __shared__ float2 sA[NPB * (KC / 2)];
    __shared__ float2 sX[NPB * (KC / 2)];

    int t = threadIdx.x;
    int node0 = blockIdx.x * NPB;
    int tn = t >> 5;
    int to = t & 31;

    float acc[4][4];
#pragma unroll
    for (int a = 0; a < 4; ++a)
#pragma unroll
        for (int b = 0; b < 4; ++b) acc[a][b] = 0.0f;

    for (int c = 0; c < 4; ++c) {
        __syncthreads();
#pragma unroll
        for (int r = 0; r < 4; ++r) {
            int i = r * 256 + t;
            ((float4*)sWrel)[i]  = ((const float4*)(pwrel  + c * KC * D))[i];
            ((float4*)sWroot)[i] = ((const float4*)(pwroot + c * KC * D))[i];
        }
#pragma unroll
        for (int r = 0; r < 2; ++r) {
            int i = r * 256 + t;
            int n = i >> 4, k2 = i & 15;
            int node = node0 + n;
            float2 av = make_float2(0.f, 0.f), xv = make_float2(0.f, 0.f);
            if (node < N_NODES) {
                av = ((const float2*)out)[(size_t)node * (D / 2) + c * (KC / 2) + k2];
                xv = x2[(size_t)node * (D / 2) + c * (KC / 2) + k2];
            }
            sA[i] = av;
            sX[i] = xv;
        }
        __syncthreads();

#pragma unroll
        for (int k2 = 0; k2 < KC / 2; ++k2) {
            float4 wr0 = *(const float4*)&sWrel[(2 * k2 + 0) * D + to * 4];
            float4 wr1 = *(const float4*)&sWrel[(2 * k2 + 1) * D + to * 4];
            float4 wt0 = *(const float4*)&sWroot[(2 * k2 + 0) * D + to * 4];
            float4 wt1 = *(const float4*)&sWroot[(2 * k2 + 1) * D + to * 4];
#pragma unroll
            for (int ni = 0; ni < 4; ++ni) {
                float2 a  = sA[(tn * 4 + ni) * (KC / 2) + k2];
                float2 xx = sX[(tn * 4 + ni) * (KC / 2) + k2];
                acc[ni][0] += a.x * wr0.x + a.y * wr1.x + xx.x * wt0.x + xx.y * wt1.x;
                acc[ni][1] += a.x * wr0.y + a.y * wr1.y + xx.x * wt0.y + xx.y * wt1.y;
                acc[ni][2] += a.x * wr0.z + a.y * wr1.z + xx.x * wt0.z + xx.y * wt1.z;
                acc[ni][3] += a.x * wr0.w + a.y * wr1.w + xx.x * wt0.w + xx.y * wt1.w;
            }
        }
    }

    int o0 = to * 4;
    float4 bias = *(const float4*)&b_rel[o0];
#pragma unroll
    for (int ni = 0; ni < 4; ++ni) {
        int node = node0 + tn * 4 + ni;
        if (node >= N_NODES) continue;
        float4 v;
        v.x = fmaxf(acc[ni][0] + bias.x, 0.f);
        v.y = fmaxf(acc[ni][1] + bias.y, 0.f);
        v.z = fmaxf(acc[ni][2] + bias.z, 0.f);
        v.w = fmaxf(acc[ni][3] + bias.w, 0.f);
        *(float4*)&out[(size_t)node * D + o0] = v;
    }
}

__global__ __launch_bounds__(128) void gemm_fallback_kernel(const float* __restrict__ x,
                                                            const float* __restrict__ Wrel,
                                                            const float* __restrict__ Wroot,
                                                            const float* __restrict__ b_rel,
                                                            float* __restrict__ out) {
    __shared__ float rowA[D];
    __shared__ float rowX[D];
    int node = blockIdx.x;
    int o = threadIdx.x;
    rowA[o] = out[(size_t)node * D + o];
    rowX[o] = x[(size_t)node * D + o];
    __syncthreads();
    float acc = b_rel[o];
    const float4* wr = (const float4*)&Wrel[o * D];
    const float4* wt = (const float4*)&Wroot[o * D];
#pragma unroll 8
    for (int k4 = 0; k4 < D / 4; ++k4) {
        float4 w = wr[k4], u = wt[k4];
        const float* a = &rowA[k4 * 4];
        const float* xx = &rowX[k4 * 4];
        acc += a[0] * w.x + a[1] * w.y + a[2] * w.z + a[3] * w.w
             + xx[0] * u.x + xx[1] * u.y + xx[2] * u.z + xx[3] * u.w;
    }
    __syncthreads();
    out[(size_t)node * D + o] = fmaxf(acc, 0.f);
}

extern "C" void kernel_launch(void* const* d_in, const int* in_sizes, int n_in,
                              void* d_out, int out_size, void* d_ws, size_t ws_size,
                              hipStream_t stream) {
    const float* x      = (const float*)d_in[0];
    const int*   ei     = (const int*)d_in[1];
    const float* W_rel  = (const float*)d_in[2];
    const float* b_rel  = (const float*)d_in[3];
    const float* W_root = (const float*)d_in[4];
    float*       out    = (float*)d_out;

    // Full-tier ws layout (16 B aligned):
    //   flag(16) | pwc 64K (bf16 frags) | xb 12.8M | aggb 12.8M | deg 200K |
    //   offsets 200K | csr_src 3.2M          total ~29.3 MB
    char* p = (char*)d_ws;
    size_t o0 = 16;
    int*            flag  = (int*)p;
    unsigned short* pwc   = (unsigned short*)(p + o0);  o0 += 8 * 8 * 64 * 8 * 2;
    unsigned short* xb    = (unsigned short*)(p + o0);  o0 += (size_t)N_NODES * D * 2;
    unsigned short* aggb  = (unsigned short*)(p + o0);  o0 += (size_t)N_NODES * D * 2;
    int*            deg   = (int*)(p + o0);             o0 += (size_t)N_NODES * 4;
    int*            offs  = (int*)(p + o0);             o0 += ((size_t)N_NODES + 1) * 4 + 12;
    o0 &= ~15ull;
    int*            csr   = (int*)(p + o0);             o0 += (size_t)N_EDGES * 4;
    const size_t need_full = o0;

    // Mid-tier layout (round-5): flag | pwrel 64K | pwroot 64K | deg | offs | csr
    size_t m0 = 16;
    float* m_pwrel  = (float*)(p + m0);  m0 += (size_t)D * D * 4;
    float* m_pwroot = (float*)(p + m0);  m0 += (size_t)D * D * 4;
    int*   m_deg    = (int*)(p + m0);    m0 += (size_t)N_NODES * 4;
    int*   m_offs   = (int*)(p + m0);    m0 += ((size_t)N_NODES + 1) * 4 + 12;
    m0 &= ~15ull;
    int*   m_csr    = (int*)(p + m0);    m0 += (size_t)N_EDGES * 4;
    const size_t need_mid = m0;
    const size_t need_pw  = 16 + 2 * (size_t)D * D * 4;

    if (ws_size >= need_full) {
        detect_kernel<<<1, 64, 0, stream>>>(ei, flag);
        pack_frag_kernel<<<128, 256, 0, stream>>>(W_rel, W_root, pwc);
        cvt_x_kernel<<<N_NODES * (D / 2) / 256 + 1, 256, 0, stream>>>(
            (const float2*)x, (ushort2*)xb);
        zero_i_kernel<<<(N_NODES + 255) / 256, 256, 0, stream>>>(deg, N_NODES);
        hist_kernel<<<(N_EDGES + 255) / 256, 256, 0, stream>>>(ei, flag, deg);
        scan_kernel<<<1, 1024, 0, stream>>>(deg, offs, deg);   // deg -> cursor in place
        reorder_kernel<<<(N_EDGES + 255) / 256, 256, 0, stream>>>(ei, flag, deg, csr);
        gather_bf16_kernel<<<N_NODES / 4, 256, 0, stream>>>((const ushort2*)xb, csr,
                                                            offs, (ushort2*)aggb);
        int blocks = (N_NODES + 63) / 64;   // 782
        GraphConvLayer_55783035240593_kernel<<<blocks, 256, 0, stream>>>(
            aggb, xb, pwc, b_rel, out);
    } else if (ws_size >= need_mid) {
        detect_kernel<<<1, 64, 0, stream>>>(ei, flag);
        pack_w_kernel<<<64, 256, 0, stream>>>(W_rel, m_pwrel);
        pack_w_kernel<<<64, 256, 0, stream>>>(W_root, m_pwroot);
        zero_i_kernel<<<(N_NODES + 255) / 256, 256, 0, stream>>>(m_deg, N_NODES);
        hist_kernel<<<(N_EDGES + 255) / 256, 256, 0, stream>>>(ei, flag, m_deg);
        scan_kernel<<<1, 1024, 0, stream>>>(m_deg, m_offs, m_deg);
        reorder_kernel<<<(N_EDGES + 255) / 256, 256, 0, stream>>>(ei, flag, m_deg, m_csr);
        gather_kernel<<<N_NODES / 4, 256, 0, stream>>>((const float2*)x, m_csr,
                                                       m_offs, (float2*)out);
        gemm_f32_kernel<<<(N_NODES + NPB - 1) / NPB, 256, 0, stream>>>(
            (const float2*)x, m_pwrel, m_pwroot, b_rel, out);
    } else {
        bool have_flag = ws_size >= 16;
        bool have_pw   = ws_size >= need_pw;
        if (have_flag) detect_kernel<<<1, 64, 0, stream>>>(ei, flag);
        if (have_pw) {
            pack_w_kernel<<<64, 256, 0, stream>>>(W_rel, m_pwrel);
            pack_w_kernel<<<64, 256, 0, stream>>>(W_root, m_pwroot);
        }
        int n4 = N_NODES * D / 4;
        zero_f4_kernel<<<(n4 + 255) / 256, 256, 0, stream>>>((float4*)out, n4);
        scatter_kernel<<<N_EDGES / 4, 256, 0, stream>>>((const float2*)x, ei,
                                                        have_flag ? flag : nullptr, out);
        if (have_pw)
            gemm_f32_kernel<<<(N_NODES + NPB - 1) / NPB, 256, 0, stream>>>(
                (const float2*)x, m_pwrel, m_pwroot, b_rel, out);
        else
            gemm_fallback_kernel<<<N_NODES, 128, 0, stream>>>(x, W_rel, W_root, b_rel, out);
    }
}

// Round 7
// 272.907 us; speedup vs baseline: 3.1661x; 1.2053x over previous
//
#include <hip/hip_runtime.h>
#include <hip/hip_bf16.h>

// GraphConv (PyG, aggr='add') + ReLU on MI355X — fp32 in/out, bf16 internals.
//   out = relu( segment_sum(x[src] -> dst) @ W_rel^T + b_rel + x @ W_root^T )
// N=50000, E=800000, D=128.
//
// Round 7: gather was 80 µs latency-bound (runtime-bound edge loop -> 1
// outstanding row load/wave). Now: 64 indices per coalesced lane-load +
// __shfl broadcast, 4 independent row loads in flight (masked 4-wide tail).
// Launch count 9 -> 6: prep_kernel fuses cvt_x+pack_frag+deg-zero; int64
// detection moved into hist/reorder as a per-wave ballot (no flag kernel).

#define N_NODES 50000
#define N_EDGES 800000
#define D 128
#define NPB 32      // nodes per fp32-gemm block (mid tier)
#define KC 32       // k per chunk (mid tier)

#define CVT_N  (N_NODES * (D / 2))   // 3,200,000 ushort2 conversions
#define PACK_N (8 * 8 * 64 * 8)      // 32,768 packed B-fragment elements

typedef __attribute__((ext_vector_type(8))) short short8;   // 8 bf16 = 4 VGPRs
typedef __attribute__((ext_vector_type(4))) float floatx4;

__device__ __forceinline__ float bf2f(unsigned short u) {
    return __uint_as_float((unsigned int)u << 16);
}
__device__ __forceinline__ unsigned short f2bf(float f) {
    __hip_bfloat16 h = __float2bfloat16(f);
    return *(unsigned short*)&h;
}

// int64 node-id array => every odd int32 word is 0 (ids < 50000).
// Requires all 64 lanes active. 1 L1-hot load + ballot.
__device__ __forceinline__ int wave_detect_i64(const int* __restrict__ ei) {
    int lane = threadIdx.x & 63;
    int v = ei[2 * lane + 1];
    return __ballot(v == 0) == ~0ull;
}

// ---------------- utility ----------------
__global__ __launch_bounds__(256) void zero_f4_kernel(float4* __restrict__ p, int n4) {
    int i = blockIdx.x * 256 + threadIdx.x;
    if (i < n4) p[i] = make_float4(0.f, 0.f, 0.f, 0.f);
}

// flag-based detect kept only for the low-tier scatter fallback
__global__ void detect_kernel(const int* __restrict__ ei, int* __restrict__ flag) {
    if (threadIdx.x == 0 && blockIdx.x == 0) {
        int any = 0;
        for (int i = 0; i < 64; ++i) any |= ei[2 * i + 1];
        flag[0] = (any == 0) ? 1 : 0;
    }
}

// ---------------- fused prep: cvt_x + pack_frag + zero deg ----------------
__global__ __launch_bounds__(256) void prep_kernel(const float2* __restrict__ x2,
                                                   ushort2* __restrict__ xb2,
                                                   const float* __restrict__ Wrel,
                                                   const float* __restrict__ Wroot,
                                                   unsigned short* __restrict__ pwc,
                                                   int* __restrict__ deg) {
    int i = blockIdx.x * 256 + threadIdx.x;
    if (i < CVT_N) {
        float2 f = x2[i];
        xb2[i] = make_ushort2(f2bf(f.x), f2bf(f.y));
    } else if (i < CVT_N + PACK_N) {
        // pwc[((t*8+n0)*64+lane)*8+j] = W_cat[n0*16+(lane&15)][t*32+(lane>>4)*8+j]
        int idx  = i - CVT_N;
        int j    = idx & 7;
        int lane = (idx >> 3) & 63;
        int n0   = (idx >> 9) & 7;
        int t    = idx >> 12;
        int n = n0 * 16 + (lane & 15);
        int k = t * 32 + (lane >> 4) * 8 + j;
        float w = (k < D) ? Wrel[n * D + k] : Wroot[n * D + (k - D)];
        pwc[idx] = f2bf(w);
    } else if (i < CVT_N + PACK_N + N_NODES) {
        deg[i - CVT_N - PACK_N] = 0;
    }
}

// ---------------- CSR build ----------------
__global__ __launch_bounds__(256) void hist_kernel(const int* __restrict__ ei,
                                                   int* __restrict__ deg) {
    int i64 = wave_detect_i64(ei);
    int e = blockIdx.x * 256 + threadIdx.x;
    if (e >= N_EDGES) return;
    int d = i64 ? ei[2 * N_EDGES + 2 * e] : ei[N_EDGES + e];
    if ((unsigned)d >= N_NODES) return;
    atomicAdd(&deg[d], 1);
}

__device__ __forceinline__ int wave_iscan(int v, int lane) {
#pragma unroll
    for (int off = 1; off < 64; off <<= 1) {
        int u = __shfl_up(v, off, 64);
        if (lane >= off) v += u;
    }
    return v;
}

// Single-block scan. offsets[0]=0, offsets[i+1]=incl sum; cursor[i]=excl sum.
__global__ __launch_bounds__(1024) void scan_kernel(const int* __restrict__ deg,
                                                    int* __restrict__ offsets,
                                                    int* __restrict__ cursor) {
    __shared__ int wsum[16];
    __shared__ int base_s;
    int t = threadIdx.x, lane = t & 63, w = t >> 6;
    if (t == 0) { base_s = 0; offsets[0] = 0; }
    __syncthreads();
    for (int c0 = 0; c0 < N_NODES; c0 += 1024) {
        int idx = c0 + t;
        int v = (idx < N_NODES) ? deg[idx] : 0;
        int inc = wave_iscan(v, lane);
        if (lane == 63) wsum[w] = inc;
        __syncthreads();
        if (w == 0) {
            int s = (lane < 16) ? wsum[lane] : 0;
            int si = wave_iscan(s, lane);
            if (lane < 16) wsum[lane] = si - s;   // exclusive wave base
        }
        __syncthreads();
        int tot = base_s + wsum[w] + inc;
        if (idx < N_NODES) {
            offsets[idx + 1] = tot;
            cursor[idx] = tot - v;                // exclusive prefix
        }
        __syncthreads();
        if (t == 1023) base_s = tot;
        __syncthreads();
    }
}

__global__ __launch_bounds__(256) void reorder_kernel(const int* __restrict__ ei,
                                                      int* __restrict__ cursor,
                                                      int* __restrict__ csr_src) {
    int i64 = wave_detect_i64(ei);
    int e = blockIdx.x * 256 + threadIdx.x;
    if (e >= N_EDGES) return;
    int s, d;
    if (i64) { s = ei[2 * e]; d = ei[2 * N_EDGES + 2 * e]; }
    else     { s = ei[e];     d = ei[N_EDGES + e]; }
    if ((unsigned)s >= N_NODES || (unsigned)d >= N_NODES) return;
    int pos = atomicAdd(&cursor[d], 1);
    csr_src[pos] = s;
}

// ---------------- gather (bf16, pipelined) ----------------
// One wave per node. 64 indices per coalesced lane-load, __shfl broadcast,
// 4 independent 256 B row loads in flight; masked tail keeps 4-wide.
__global__ __launch_bounds__(256) void gather_bf16_kernel(const ushort2* __restrict__ xb2,
                                                          const int* __restrict__ csr_src,
                                                          const int* __restrict__ offsets,
                                                          ushort2* __restrict__ aggb2) {
    int node = blockIdx.x * 4 + (threadIdx.x >> 6);
    int lane = threadIdx.x & 63;
    if (node >= N_NODES) return;
    int beg = offsets[node], end = offsets[node + 1];
    float ax = 0.f, ay = 0.f;
    for (int e = beg; e < end; e += 64) {
        int cnt = end - e;
        if (cnt > 64) cnt = 64;
        int myidx = (lane < cnt) ? csr_src[e + lane] : 0;   // one coalesced load
        for (int j = 0; j < cnt; j += 4) {
            int s0 = __shfl(myidx, j);
            int s1 = __shfl(myidx, j + 1);   // lane >= cnt holds 0 -> row 0 (valid)
            int s2 = __shfl(myidx, j + 2);
            int s3 = __shfl(myidx, j + 3);
            ushort2 u0 = xb2[(size_t)s0 * (D / 2) + lane];
            ushort2 u1 = xb2[(size_t)s1 * (D / 2) + lane];
            ushort2 u2 = xb2[(size_t)s2 * (D / 2) + lane];
            ushort2 u3 = xb2[(size_t)s3 * (D / 2) + lane];
            float m1 = (j + 1 < cnt) ? 1.f : 0.f;
            float m2 = (j + 2 < cnt) ? 1.f : 0.f;
            float m3 = (j + 3 < cnt) ? 1.f : 0.f;
            ax += bf2f(u0.x) + m1 * bf2f(u1.x) + m2 * bf2f(u2.x) + m3 * bf2f(u3.x);
            ay += bf2f(u0.y) + m1 * bf2f(u1.y) + m2 * bf2f(u2.y) + m3 * bf2f(u3.y);
        }
    }
    aggb2[(size_t)node * (D / 2) + lane] = make_ushort2(f2bf(ax), f2bf(ay));
}

// ---------------- MFMA GEMM: C = [aggb | xb] @ W_cat^T + b, relu ----------------
// 1 wave = 16 nodes x 128 outs; 8 k-steps of 32; no LDS; acc in 32 VGPRs.
// Layouts (verified): A[m=lane&15][k=quad*8+j], D: col=lane&15, row=quad*4+reg.
__global__ __launch_bounds__(256) void GraphConvLayer_55783035240593_kernel(
        const unsigned short* __restrict__ aggb,
        const unsigned short* __restrict__ xb,
        const unsigned short* __restrict__ pwc,
        const float* __restrict__ b_rel,
        float* __restrict__ out) {
    int wid  = threadIdx.x >> 6;
    int lane = threadIdx.x & 63;
    int nodebase = blockIdx.x * 64 + wid * 16;
    if (nodebase >= N_NODES) return;
    int m = lane & 15, quad = lane >> 4;

    const unsigned short* arow = aggb + (size_t)(nodebase + m) * D + quad * 8;
    const unsigned short* xrow = xb   + (size_t)(nodebase + m) * D + quad * 8;

    floatx4 acc[8];
#pragma unroll
    for (int n0 = 0; n0 < 8; ++n0) acc[n0] = (floatx4){0.f, 0.f, 0.f, 0.f};

#pragma unroll
    for (int t = 0; t < 8; ++t) {
        const unsigned short* asrc = (t < 4) ? (arow + t * 32) : (xrow + (t - 4) * 32);
        short8 afrag = *(const short8*)asrc;
        const unsigned short* bbase = pwc + ((size_t)t * 8 * 64 + lane) * 8;
#pragma unroll
        for (int n0 = 0; n0 < 8; ++n0) {
            short8 bfrag = *(const short8*)(bbase + (size_t)n0 * 64 * 8);
            acc[n0] = __builtin_amdgcn_mfma_f32_16x16x32_bf16(afrag, bfrag, acc[n0], 0, 0, 0);
        }
    }

#pragma unroll
    for (int n0 = 0; n0 < 8; ++n0) {
        int n = n0 * 16 + m;
        float bias = b_rel[n];
#pragma unroll
        for (int r = 0; r < 4; ++r) {
            int node = nodebase + quad * 4 + r;
            out[(size_t)node * D + n] = fmaxf(acc[n0][r] + bias, 0.f);
        }
    }
}

// ---------------- mid tier: fp32 CSR + VALU GEMM ----------------
__global__ __launch_bounds__(256) void pack_w_kernel(const float* __restrict__ W,
                                                     float* __restrict__ pw) {
    int idx = blockIdx.x * 256 + threadIdx.x;
    if (idx >= D * D) return;
    int o = idx >> 7, k = idx & 127;
    pw[k * D + o] = W[o * D + k];
}

__global__ __launch_bounds__(256) void gather_kernel(const float2* __restrict__ x2,
                                                     const int* __restrict__ csr_src,
                                                     const int* __restrict__ offsets,
                                                     float2* __restrict__ agg2) {
    int node = blockIdx.x * 4 + (threadIdx.x >> 6);
    int lane = threadIdx.x & 63;
    if (node >= N_NODES) return;
    int beg = offsets[node], end = offsets[node + 1];
    float2 acc = make_float2(0.f, 0.f);
    for (int e = beg; e < end; ++e) {
        int s = csr_src[e];
        float2 f = x2[(size_t)s * (D / 2) + lane];
        acc.x += f.x;
        acc.y += f.y;
    }
    agg2[(size_t)node * (D / 2) + lane] = acc;
}

__global__ __launch_bounds__(256) void scatter_kernel(const float2* __restrict__ x2,
                                                      const int* __restrict__ ei,
                                                      const int* __restrict__ flag,
                                                      float* __restrict__ agg) {
    int wave = threadIdx.x >> 6;
    int lane = threadIdx.x & 63;
    int e = blockIdx.x * 4 + wave;
    if (e >= N_EDGES) return;
    int i64 = flag ? flag[0] : 0;
    int s, d;
    if (i64) { s = ei[2 * e]; d = ei[2 * N_EDGES + 2 * e]; }
    else     { s = ei[e];     d = ei[N_EDGES + e]; }
    if ((unsigned)s >= N_NODES || (unsigned)d >= N_NODES) return;
    float2 f = x2[(size_t)s * (D / 2) + lane];
    atomicAdd(&agg[(size_t)d * D + 2 * lane + 0], f.x);
    atomicAdd(&agg[(size_t)d * D + 2 * lane + 1], f.y);
}

__global__ __launch_bounds__(256) void gemm_f32_kernel(
        const float2* __restrict__ x2,
        const float* __restrict__ pwrel,
        const float* __restrict__ pwroot,
        const float* __restrict__ b_rel,
        float* __restrict__ out) {
    __shared__ float sWrel[KC * D];
    __shared__ float sWroot[KC * D];
    __shared__ float2 sA[NPB * (KC / 2)];
    __shared__ float2 sX[NPB * (KC / 2)];

    int t = threadIdx.x;
    int node0 = blockIdx.x * NPB;
    int tn = t >> 5;
    int to = t & 31;

    float acc[4][4];
#pragma unroll
    for (int a = 0; a < 4; ++a)
#pragma unroll
        for (int b = 0; b < 4; ++b) acc[a][b] = 0.0f;

    for (int c = 0; c < 4; ++c) {
        __syncthreads();
#pragma unroll
        for (int r = 0; r < 4; ++r) {
            int i = r * 256 + t;
            ((float4*)sWrel)[i]  = ((const float4*)(pwrel  + c * KC * D))[i];
            ((float4*)sWroot)[i] = ((const float4*)(pwroot + c * KC * D))[i];
        }
#pragma unroll
        for (int r = 0; r < 2; ++r) {
            int i = r * 256 + t;
            int n = i >> 4, k2 = i & 15;
            int node = node0 + n;
            float2 av = make_float2(0.f, 0.f), xv = make_float2(0.f, 0.f);
            if (node < N_NODES) {
                av = ((const float2*)out)[(size_t)node * (D / 2) + c * (KC / 2) + k2];
                xv = x2[(size_t)node * (D / 2) + c * (KC / 2) + k2];
            }
            sA[i] = av;
            sX[i] = xv;
        }
        __syncthreads();

#pragma unroll
        for (int k2 = 0; k2 < KC / 2; ++k2) {
            float4 wr0 = *(const float4*)&sWrel[(2 * k2 + 0) * D + to * 4];
            float4 wr1 = *(const float4*)&sWrel[(2 * k2 + 1) * D + to * 4];
            float4 wt0 = *(const float4*)&sWroot[(2 * k2 + 0) * D + to * 4];
            float4 wt1 = *(const float4*)&sWroot[(2 * k2 + 1) * D + to * 4];
#pragma unroll
            for (int ni = 0; ni < 4; ++ni) {
                float2 a  = sA[(tn * 4 + ni) * (KC / 2) + k2];
                float2 xx = sX[(tn * 4 + ni) * (KC / 2) + k2];
                acc[ni][0] += a.x * wr0.x + a.y * wr1.x + xx.x * wt0.x + xx.y * wt1.x;
                acc[ni][1] += a.x * wr0.y + a.y * wr1.y + xx.x * wt0.y + xx.y * wt1.y;
                acc[ni][2] += a.x * wr0.z + a.y * wr1.z + xx.x * wt0.z + xx.y * wt1.z;
                acc[ni][3] += a.x * wr0.w + a.y * wr1.w + xx.x * wt0.w + xx.y * wt1.w;
            }
        }
    }

    int o0 = to * 4;
    float4 bias = *(const float4*)&b_rel[o0];
#pragma unroll
    for (int ni = 0; ni < 4; ++ni) {
        int node = node0 + tn * 4 + ni;
        if (node >= N_NODES) continue;
        float4 v;
        v.x = fmaxf(acc[ni][0] + bias.x, 0.f);
        v.y = fmaxf(acc[ni][1] + bias.y, 0.f);
        v.z = fmaxf(acc[ni][2] + bias.z, 0.f);
        v.w = fmaxf(acc[ni][3] + bias.w, 0.f);
        *(float4*)&out[(size_t)node * D + o0] = v;
    }
}

__global__ __launch_bounds__(128) void gemm_fallback_kernel(const float* __restrict__ x,
                                                            const float* __restrict__ Wrel,
                                                            const float* __restrict__ Wroot,
                                                            const float* __restrict__ b_rel,
                                                            float* __restrict__ out) {
    __shared__ float rowA[D];
    __shared__ float rowX[D];
    int node = blockIdx.x;
    int o = threadIdx.x;
    rowA[o] = out[(size_t)node * D + o];
    rowX[o] = x[(size_t)node * D + o];
    __syncthreads();
    float acc = b_rel[o];
    const float4* wr = (const float4*)&Wrel[o * D];
    const float4* wt = (const float4*)&Wroot[o * D];
#pragma unroll 8
    for (int k4 = 0; k4 < D / 4; ++k4) {
        float4 w = wr[k4], u = wt[k4];
        const float* a = &rowA[k4 * 4];
        const float* xx = &rowX[k4 * 4];
        acc += a[0] * w.x + a[1] * w.y + a[2] * w.z + a[3] * w.w
             + xx[0] * u.x + xx[1] * u.y + xx[2] * u.z + xx[3] * u.w;
    }
    __syncthreads();
    out[(size_t)node * D + o] = fmaxf(acc, 0.f);
}

extern "C" void kernel_launch(void* const* d_in, const int* in_sizes, int n_in,
                              void* d_out, int out_size, void* d_ws, size_t ws_size,
                              hipStream_t stream) {
    const float* x      = (const float*)d_in[0];
    const int*   ei     = (const int*)d_in[1];
    const float* W_rel  = (const float*)d_in[2];
    const float* b_rel  = (const float*)d_in[3];
    const float* W_root = (const float*)d_in[4];
    float*       out    = (float*)d_out;

    // Full-tier ws layout (16 B aligned):
    //   flag(16) | pwc 64K | xb 12.8M | aggb 12.8M | deg 200K | offs 200K | csr 3.2M
    char* p = (char*)d_ws;
    size_t o0 = 16;
    int*            flag  = (int*)p;
    unsigned short* pwc   = (unsigned short*)(p + o0);  o0 += (size_t)PACK_N * 2;
    unsigned short* xb    = (unsigned short*)(p + o0);  o0 += (size_t)N_NODES * D * 2;
    unsigned short* aggb  = (unsigned short*)(p + o0);  o0 += (size_t)N_NODES * D * 2;
    int*            deg   = (int*)(p + o0);             o0 += (size_t)N_NODES * 4;
    int*            offs  = (int*)(p + o0);             o0 += ((size_t)N_NODES + 1) * 4 + 12;
    o0 &= ~15ull;
    int*            csr   = (int*)(p + o0);             o0 += (size_t)N_EDGES * 4;
    const size_t need_full = o0;

    // Mid-tier layout: flag | pwrel 64K | pwroot 64K | deg | offs | csr
    size_t m0 = 16;
    float* m_pwrel  = (float*)(p + m0);  m0 += (size_t)D * D * 4;
    float* m_pwroot = (float*)(p + m0);  m0 += (size_t)D * D * 4;
    int*   m_deg    = (int*)(p + m0);    m0 += (size_t)N_NODES * 4;
    int*   m_offs   = (int*)(p + m0);    m0 += ((size_t)N_NODES + 1) * 4 + 12;
    m0 &= ~15ull;
    int*   m_csr    = (int*)(p + m0);    m0 += (size_t)N_EDGES * 4;
    const size_t need_mid = m0;
    const size_t need_pw  = 16 + 2 * (size_t)D * D * 4;

    if (ws_size >= need_full) {
        const int prep_total = CVT_N + PACK_N + N_NODES;
        prep_kernel<<<(prep_total + 255) / 256, 256, 0, stream>>>(
            (const float2*)x, (ushort2*)xb, W_rel, W_root, pwc, deg);
        hist_kernel<<<(N_EDGES + 255) / 256, 256, 0, stream>>>(ei, deg);
        scan_kernel<<<1, 1024, 0, stream>>>(deg, offs, deg);   // deg -> cursor in place
        reorder_kernel<<<(N_EDGES + 255) / 256, 256, 0, stream>>>(ei, deg, csr);
        gather_bf16_kernel<<<N_NODES / 4, 256, 0, stream>>>((const ushort2*)xb, csr,
                                                            offs, (ushort2*)aggb);
        GraphConvLayer_55783035240593_kernel<<<(N_NODES + 63) / 64, 256, 0, stream>>>(
            aggb, xb, pwc, b_rel, out);
    } else if (ws_size >= need_mid) {
        pack_w_kernel<<<64, 256, 0, stream>>>(W_rel, m_pwrel);
        pack_w_kernel<<<64, 256, 0, stream>>>(W_root, m_pwroot);
        zero_f4_kernel<<<(N_NODES / 4 + 255) / 256, 256, 0, stream>>>((float4*)m_deg,
                                                                      N_NODES / 4);
        hist_kernel<<<(N_EDGES + 255) / 256, 256, 0, stream>>>(ei, m_deg);
        scan_kernel<<<1, 1024, 0, stream>>>(m_deg, m_offs, m_deg);
        reorder_kernel<<<(N_EDGES + 255) / 256, 256, 0, stream>>>(ei, m_deg, m_csr);
        gather_kernel<<<N_NODES / 4, 256, 0, stream>>>((const float2*)x, m_csr,
                                                       m_offs, (float2*)out);
        gemm_f32_kernel<<<(N_NODES + NPB - 1) / NPB, 256, 0, stream>>>(
            (const float2*)x, m_pwrel, m_pwroot, b_rel, out);
    } else {
        bool have_flag = ws_size >= 16;
        bool have_pw   = ws_size >= need_pw;
        if (have_flag) detect_kernel<<<1, 64, 0, stream>>>(ei, flag);
        if (have_pw) {
            pack_w_kernel<<<64, 256, 0, stream>>>(W_rel, m_pwrel);
            pack_w_kernel<<<64, 256, 0, stream>>>(W_root, m_pwroot);
        }
        int n4 = N_NODES * D / 4;
        zero_f4_kernel<<<(n4 + 255) / 256, 256, 0, stream>>>((float4*)out, n4);
        scatter_kernel<<<N_EDGES / 4, 256, 0, stream>>>((const float2*)x, ei,
                                                        have_flag ? flag : nullptr, out);
        if (have_pw)
            gemm_f32_kernel<<<(N_NODES + NPB - 1) / NPB, 256, 0, stream>>>(
                (const float2*)x, m_pwrel, m_pwroot, b_rel, out);
        else
            gemm_fallback_kernel<<<N_NODES, 128, 0, stream>>>(x, W_rel, W_root, b_rel, out);
    }
}